// Round 18
// baseline (230.814 us; speedup 1.0000x reference)
//
#include <hip/hip_runtime.h>

#define NN 50000
#define NE 400000
#define FD 64
#define NH 2
#define HF 128   // H * F
#define ELLW 48  // ELL row width; P(Poisson(8) deg > 48) < 1e-15 per node
#define SCAN_NB ((NN + 255) / 256)
#define NTA 64   // nodes per block in node_transform
#define GG_BLOCKS 2048   // persistent gather grid

__device__ __forceinline__ float lrelu(float x, float s) { return fmaxf(x, x * s); }

// ---- bf16 helpers: RNE pack, exact unpack ----
__device__ __forceinline__ unsigned short f2bf(float f) {
    unsigned u = __float_as_uint(f);
    return (unsigned short)((u + 0x7FFFu + ((u >> 16) & 1u)) >> 16);
}
__device__ __forceinline__ float2 bf2f(unsigned u) {
    return make_float2(__uint_as_float(u << 16), __uint_as_float(u & 0xFFFF0000u));
}
__device__ __forceinline__ float4 bfx4(unsigned lo, unsigned hi) {
    const float2 a = bf2f(lo), b = bf2f(hi);
    return make_float4(a.x, a.y, b.x, b.y);
}

// ================= ELL build: 2 dispatches total =================
__global__ void zero_deg(int* __restrict__ deg) {
    const int i = blockIdx.x * 256 + threadIdx.x;
    if (i < NN) deg[i] = 0;
}

__global__ void build_ell(const int* __restrict__ ei, const float* __restrict__ ea,
                          int* __restrict__ deg, int2* __restrict__ ell) {
    const int t = blockIdx.x * blockDim.x + threadIdx.x;
    if (t >= NE) return;
    const int d = ei[NE + t];
    const int r = atomicAdd(&deg[d], 1);
    ell[(size_t)d * ELLW + r] = make_int2(ei[t], __float_as_int(ea[t]));
}

// ---- per-layer GEMM: [xl|xr] = hin @ [Wl|Wr] + [bl|br] ----
__global__ __launch_bounds__(256) void node_transform(
    const float* __restrict__ hin,
    const float* __restrict__ Wl, const float* __restrict__ bl,
    const float* __restrict__ Wr, const float* __restrict__ br,
    unsigned short* __restrict__ xlb, unsigned short* __restrict__ xrb) {
    __shared__ float sA[FD][68];
    const int t = threadIdx.x;
    const int n0 = blockIdx.x * NTA;
    for (int idx = t; idx < NTA * 16; idx += 256) {
        const int n = idx & 63;
        const int kq = (idx >> 6) << 2;
        const int ni = n0 + n;
        const float4 v = (ni < NN) ? *(const float4*)(hin + (size_t)ni * FD + kq)
                                   : make_float4(0.f, 0.f, 0.f, 0.f);
        sA[kq][n] = v.x; sA[kq + 1][n] = v.y;
        sA[kq + 2][n] = v.z; sA[kq + 3][n] = v.w;
    }
    __syncthreads();
    const int q = t & 63;
    const int g = t >> 6;
    const int c0 = q << 2;
    const bool isR = c0 >= 128;
    const int cc = isR ? c0 - 128 : c0;
    const float* __restrict__ W = isR ? Wr : Wl;
    const float4 bv = isR ? *(const float4*)(br + cc) : *(const float4*)(bl + cc);
    unsigned short* __restrict__ dst = isR ? xrb : xlb;
    float acc[16][4];
#pragma unroll
    for (int i = 0; i < 16; ++i) {
        acc[i][0] = bv.x; acc[i][1] = bv.y; acc[i][2] = bv.z; acc[i][3] = bv.w;
    }
    const int nb = g << 4;
#pragma unroll 4
    for (int k = 0; k < FD; ++k) {
        const float4 w = *(const float4*)(W + k * HF + cc);
        const float4 a0 = *(const float4*)(&sA[k][nb]);
        const float4 a1 = *(const float4*)(&sA[k][nb + 4]);
        const float4 a2 = *(const float4*)(&sA[k][nb + 8]);
        const float4 a3 = *(const float4*)(&sA[k][nb + 12]);
        const float av[16] = {a0.x, a0.y, a0.z, a0.w, a1.x, a1.y, a1.z, a1.w,
                              a2.x, a2.y, a2.z, a2.w, a3.x, a3.y, a3.z, a3.w};
#pragma unroll
        for (int i = 0; i < 16; ++i) {
            acc[i][0] = fmaf(av[i], w.x, acc[i][0]);
            acc[i][1] = fmaf(av[i], w.y, acc[i][1]);
            acc[i][2] = fmaf(av[i], w.z, acc[i][2]);
            acc[i][3] = fmaf(av[i], w.w, acc[i][3]);
        }
    }
    const int xoff = (cc < 64) ? (cc << 1) : (((cc - 64) << 1) + 4);
#pragma unroll
    for (int i = 0; i < 16; ++i) {
        const int n = n0 + nb + i;
        if (n >= NN) continue;
        uint2 pk;
        pk.x = (unsigned)f2bf(acc[i][0]) | ((unsigned)f2bf(acc[i][1]) << 16);
        pk.y = (unsigned)f2bf(acc[i][2]) | ((unsigned)f2bf(acc[i][3]) << 16);
        *(uint2*)(dst + (size_t)n * HF + xoff) = pk;
    }
}

// ---- one edge-slot update; VALID folds at compile time on the hot path ----
__device__ __forceinline__ void gat_edge(
    bool valid, int lane, float eav, uint4 L,
    const float4& we0, const float4& we1, const float4& aw0, const float4& aw1,
    const float4& xr0, const float4& xr1,
    float4& a0, float4& a1, float& d0, float& d1) {
    const float4 xls0 = bfx4(L.x, L.y);
    const float4 xls1 = bfx4(L.z, L.w);
    float p0, p1, t;
    t = lrelu(fmaf(eav, we0.x, xls0.x + xr0.x), 0.2f); p0 = t * aw0.x;
    t = lrelu(fmaf(eav, we0.y, xls0.y + xr0.y), 0.2f); p0 = fmaf(t, aw0.y, p0);
    t = lrelu(fmaf(eav, we0.z, xls0.z + xr0.z), 0.2f); p0 = fmaf(t, aw0.z, p0);
    t = lrelu(fmaf(eav, we0.w, xls0.w + xr0.w), 0.2f); p0 = fmaf(t, aw0.w, p0);
    t = lrelu(fmaf(eav, we1.x, xls1.x + xr1.x), 0.2f); p1 = t * aw1.x;
    t = lrelu(fmaf(eav, we1.y, xls1.y + xr1.y), 0.2f); p1 = fmaf(t, aw1.y, p1);
    t = lrelu(fmaf(eav, we1.z, xls1.z + xr1.z), 0.2f); p1 = fmaf(t, aw1.z, p1);
    t = lrelu(fmaf(eav, we1.w, xls1.w + xr1.w), 0.2f); p1 = fmaf(t, aw1.w, p1);
    // packed dual-head 16-lane reduce: 5 shfl
    const bool hi = (lane & 8) != 0;
    float send = hi ? p0 : p1;
    float got = __shfl_xor(send, 8);
    float q = hi ? (p1 + got) : (p0 + got);
    q += __shfl_xor(q, 4);
    q += __shfl_xor(q, 2);
    q += __shfl_xor(q, 1);
    const float oth = __shfl_xor(q, 8);
    const float s0 = hi ? oth : q;
    const float s1 = hi ? q : oth;
    const float w0 = valid ? __expf(s0) : 0.f;
    const float w1 = valid ? __expf(s1) : 0.f;
    a0.x = fmaf(w0, xls0.x, a0.x);
    a0.y = fmaf(w0, xls0.y, a0.y);
    a0.z = fmaf(w0, xls0.z, a0.z);
    a0.w = fmaf(w0, xls0.w, a0.w);
    d0 += w0;
    a1.x = fmaf(w1, xls1.x, a1.x);
    a1.y = fmaf(w1, xls1.y, a1.y);
    a1.z = fmaf(w1, xls1.z, a1.z);
    a1.w = fmaf(w1, xls1.w, a1.w);
    d1 += w1;
}

// ---- layer-0 persistent gather (unchanged hot loop from R17) ----
__global__ __launch_bounds__(256) void gat_gather(
    const int* __restrict__ deg, const int2* __restrict__ ell,
    const unsigned short* __restrict__ xlb, const unsigned short* __restrict__ xrb,
    const float* __restrict__ We, const float* __restrict__ att,
    const float* __restrict__ bias, float* __restrict__ hout) {
    const int t = threadIdx.x;
    const int lane = t & 63;
    const int slot = lane >> 4;
    const int fo = (lane & 15) << 2;
    const float4 we0 = *(const float4*)(We + fo);
    const float4 we1 = *(const float4*)(We + 64 + fo);
    const float4 aw0 = *(const float4*)(att + fo);
    const float4 aw1 = *(const float4*)(att + 64 + fo);
    const float4 bv = *(const float4*)(bias + fo);
    const int stride = (GG_BLOCKS * 256) >> 6;
    int wid = (blockIdx.x * 256 + t) >> 6;
    int dg = (wid < NN) ? deg[wid] : 0;

    while (wid < NN) {
        const int nxt = wid + stride;
        const int dgn = (nxt < NN) ? deg[nxt] : 0;
        const uint4 xrp = *(const uint4*)(xrb + (size_t)wid * HF + (fo << 1));
        const float4 xr0 = bfx4(xrp.x, xrp.y);
        const float4 xr1 = bfx4(xrp.z, xrp.w);
        const int e0 = wid * ELLW;
        const int e1 = e0 + dg;
        float d0 = 0.f, d1 = 0.f;
        float4 a0 = {0.f, 0.f, 0.f, 0.f}, a1 = {0.f, 0.f, 0.f, 0.f};
        int eb = e0;
        for (; eb + 8 <= e1; eb += 8) {
            const int2 seA = ell[eb + slot];
            const int2 seB = ell[eb + 4 + slot];
            const uint4 LA = *(const uint4*)(xlb + (size_t)seA.x * HF + (fo << 1));
            const uint4 LB = *(const uint4*)(xlb + (size_t)seB.x * HF + (fo << 1));
            gat_edge(true, lane, __int_as_float(seA.y), LA, we0, we1, aw0, aw1,
                     xr0, xr1, a0, a1, d0, d1);
            gat_edge(true, lane, __int_as_float(seB.y), LB, we0, we1, aw0, aw1,
                     xr0, xr1, a0, a1, d0, d1);
        }
        if (eb < e1) {
            const int myA = eb + slot, myB = eb + 4 + slot;
            const bool vA = myA < e1, vB = myB < e1;
            const int2 seA = ell[vA ? myA : e0];
            const int2 seB = ell[vB ? myB : e0];
            const uint4 LA = *(const uint4*)(xlb + (size_t)seA.x * HF + (fo << 1));
            const uint4 LB = *(const uint4*)(xlb + (size_t)seB.x * HF + (fo << 1));
            gat_edge(vA, lane, __int_as_float(seA.y), LA, we0, we1, aw0, aw1,
                     xr0, xr1, a0, a1, d0, d1);
            gat_edge(vB, lane, __int_as_float(seB.y), LB, we0, we1, aw0, aw1,
                     xr0, xr1, a0, a1, d0, d1);
        }
#pragma unroll
        for (int o = 16; o <= 32; o <<= 1) {
            d0 += __shfl_xor(d0, o);
            d1 += __shfl_xor(d1, o);
            a0.x += __shfl_xor(a0.x, o); a0.y += __shfl_xor(a0.y, o);
            a0.z += __shfl_xor(a0.z, o); a0.w += __shfl_xor(a0.w, o);
            a1.x += __shfl_xor(a1.x, o); a1.y += __shfl_xor(a1.y, o);
            a1.z += __shfl_xor(a1.z, o); a1.w += __shfl_xor(a1.w, o);
        }
        if (slot == 0) {
            const float i0 = d0 > 0.f ? 1.f / d0 : 0.f;
            const float i1 = d1 > 0.f ? 1.f / d1 : 0.f;
            float4 rr;
            rr.x = lrelu(fmaf(0.5f, fmaf(a0.x, i0, a1.x * i1), bv.x), 0.01f);
            rr.y = lrelu(fmaf(0.5f, fmaf(a0.y, i0, a1.y * i1), bv.y), 0.01f);
            rr.z = lrelu(fmaf(0.5f, fmaf(a0.z, i0, a1.z * i1), bv.z), 0.01f);
            rr.w = lrelu(fmaf(0.5f, fmaf(a0.w, i0, a1.w * i1), bv.w), 0.01f);
            *(float4*)(hout + (size_t)wid * FD + fo) = rr;
        }
        wid = nxt;
        dg = dgn;
    }
}

// ---- layer-1 gather FUSED with gate+pooling (separate function, NO template;
// h2 never touches global memory; partials transposed for pool_reduce) ----
__global__ __launch_bounds__(256) void gat_gather_pool(
    const int* __restrict__ deg, const int2* __restrict__ ell,
    const unsigned short* __restrict__ xlb, const unsigned short* __restrict__ xrb,
    const float* __restrict__ We, const float* __restrict__ att,
    const float* __restrict__ bias,
    const float* __restrict__ x, const float* __restrict__ h1,
    const float* __restrict__ gw, const float* __restrict__ gb,
    float* __restrict__ part) {
    __shared__ float sp[193];
    const int t = threadIdx.x;
    if (t < 193) sp[t] = 0.f;
    __syncthreads();
    const int lane = t & 63;
    const int slot = lane >> 4;
    const int fo = (lane & 15) << 2;
    const float4 we0 = *(const float4*)(We + fo);
    const float4 we1 = *(const float4*)(We + 64 + fo);
    const float4 aw0 = *(const float4*)(att + fo);
    const float4 aw1 = *(const float4*)(att + 64 + fo);
    const float4 bv = *(const float4*)(bias + fo);
    const float gbv = gb[0];
    const int stride = (GG_BLOCKS * 256) >> 6;
    int wid = (blockIdx.x * 256 + t) >> 6;
    int dg = (wid < NN) ? deg[wid] : 0;

    while (wid < NN) {
        const int nxt = wid + stride;
        const int dgn = (nxt < NN) ? deg[nxt] : 0;
        const uint4 xrp = *(const uint4*)(xrb + (size_t)wid * HF + (fo << 1));
        const float4 xr0 = bfx4(xrp.x, xrp.y);
        const float4 xr1 = bfx4(xrp.z, xrp.w);
        const int e0 = wid * ELLW;
        const int e1 = e0 + dg;
        float d0 = 0.f, d1 = 0.f;
        float4 a0 = {0.f, 0.f, 0.f, 0.f}, a1 = {0.f, 0.f, 0.f, 0.f};
        int eb = e0;
        for (; eb + 8 <= e1; eb += 8) {
            const int2 seA = ell[eb + slot];
            const int2 seB = ell[eb + 4 + slot];
            const uint4 LA = *(const uint4*)(xlb + (size_t)seA.x * HF + (fo << 1));
            const uint4 LB = *(const uint4*)(xlb + (size_t)seB.x * HF + (fo << 1));
            gat_edge(true, lane, __int_as_float(seA.y), LA, we0, we1, aw0, aw1,
                     xr0, xr1, a0, a1, d0, d1);
            gat_edge(true, lane, __int_as_float(seB.y), LB, we0, we1, aw0, aw1,
                     xr0, xr1, a0, a1, d0, d1);
        }
        if (eb < e1) {
            const int myA = eb + slot, myB = eb + 4 + slot;
            const bool vA = myA < e1, vB = myB < e1;
            const int2 seA = ell[vA ? myA : e0];
            const int2 seB = ell[vB ? myB : e0];
            const uint4 LA = *(const uint4*)(xlb + (size_t)seA.x * HF + (fo << 1));
            const uint4 LB = *(const uint4*)(xlb + (size_t)seB.x * HF + (fo << 1));
            gat_edge(vA, lane, __int_as_float(seA.y), LA, we0, we1, aw0, aw1,
                     xr0, xr1, a0, a1, d0, d1);
            gat_edge(vB, lane, __int_as_float(seB.y), LB, we0, we1, aw0, aw1,
                     xr0, xr1, a0, a1, d0, d1);
        }
#pragma unroll
        for (int o = 16; o <= 32; o <<= 1) {
            d0 += __shfl_xor(d0, o);
            d1 += __shfl_xor(d1, o);
            a0.x += __shfl_xor(a0.x, o); a0.y += __shfl_xor(a0.y, o);
            a0.z += __shfl_xor(a0.z, o); a0.w += __shfl_xor(a0.w, o);
            a1.x += __shfl_xor(a1.x, o); a1.y += __shfl_xor(a1.y, o);
            a1.z += __shfl_xor(a1.z, o); a1.w += __shfl_xor(a1.w, o);
        }
        if (slot == 0) {
            const float i0 = d0 > 0.f ? 1.f / d0 : 0.f;
            const float i1 = d1 > 0.f ? 1.f / d1 : 0.f;
            float4 rr;
            rr.x = lrelu(fmaf(0.5f, fmaf(a0.x, i0, a1.x * i1), bv.x), 0.01f);
            rr.y = lrelu(fmaf(0.5f, fmaf(a0.y, i0, a1.y * i1), bv.y), 0.01f);
            rr.z = lrelu(fmaf(0.5f, fmaf(a0.z, i0, a1.z * i1), bv.z), 0.01f);
            rr.w = lrelu(fmaf(0.5f, fmaf(a0.w, i0, a1.w * i1), bv.w), 0.01f);
            // gate dot over [x | h1 | h2(=rr)] for this node's feature quad
            const float4 xq = *(const float4*)(x + (size_t)wid * FD + fo);
            const float4 hq = *(const float4*)(h1 + (size_t)wid * FD + fo);
            const float4 g0 = *(const float4*)(gw + fo);
            const float4 g1 = *(const float4*)(gw + 64 + fo);
            const float4 g2 = *(const float4*)(gw + 128 + fo);
            float v = xq.x * g0.x + xq.y * g0.y + xq.z * g0.z + xq.w * g0.w;
            v = fmaf(hq.x, g1.x, v); v = fmaf(hq.y, g1.y, v);
            v = fmaf(hq.z, g1.z, v); v = fmaf(hq.w, g1.w, v);
            v = fmaf(rr.x, g2.x, v); v = fmaf(rr.y, g2.y, v);
            v = fmaf(rr.z, g2.z, v); v = fmaf(rr.w, g2.w, v);
            v += __shfl_xor(v, 1);
            v += __shfl_xor(v, 2);
            v += __shfl_xor(v, 4);
            v += __shfl_xor(v, 8);   // all 16 lanes of slot 0 hold full dot
            const float e = __expf(lrelu(v + gbv, 0.01f));
            atomicAdd(&sp[fo],       e * xq.x);
            atomicAdd(&sp[fo + 1],   e * xq.y);
            atomicAdd(&sp[fo + 2],   e * xq.z);
            atomicAdd(&sp[fo + 3],   e * xq.w);
            atomicAdd(&sp[64 + fo],     e * hq.x);
            atomicAdd(&sp[64 + fo + 1], e * hq.y);
            atomicAdd(&sp[64 + fo + 2], e * hq.z);
            atomicAdd(&sp[64 + fo + 3], e * hq.w);
            atomicAdd(&sp[128 + fo],     e * rr.x);
            atomicAdd(&sp[128 + fo + 1], e * rr.y);
            atomicAdd(&sp[128 + fo + 2], e * rr.z);
            atomicAdd(&sp[128 + fo + 3], e * rr.w);
            if (fo == 0) atomicAdd(&sp[192], e);
        }
        wid = nxt;
        dg = dgn;
    }
    __syncthreads();
    if (t < 193) part[(size_t)t * GG_BLOCKS + blockIdx.x] = sp[t];
}

// ---- reduce transposed partials: block e sums part[e*GG_BLOCKS ..] ----
__global__ void pool_reduce(const float* __restrict__ part, float* __restrict__ pooled) {
    __shared__ float ws[4];
    const int e = blockIdx.x;   // 0..192
    const int t = threadIdx.x;  // 256
    float s = 0.f;
    for (int b = t; b < GG_BLOCKS; b += 256) s += part[(size_t)e * GG_BLOCKS + b];
#pragma unroll
    for (int o = 32; o; o >>= 1) s += __shfl_xor(s, o);
    if ((t & 63) == 0) ws[t >> 6] = s;
    __syncthreads();
    if (t == 0) pooled[e] = ws[0] + ws[1] + ws[2] + ws[3];
}

// ---- final tiny MLP: z(193) -> 96 -> 96 -> 2 ----
__global__ void mlp_kernel(const float* __restrict__ pooled, const float* __restrict__ pt,
                           const float* __restrict__ f1w, const float* __restrict__ f1b,
                           const float* __restrict__ f2w, const float* __restrict__ f2b,
                           const float* __restrict__ flw, const float* __restrict__ flb,
                           float* __restrict__ out) {
    __shared__ float z[193], z1[96], z2[96];
    const int t = threadIdx.x;  // 256
    const float inv = 1.f / pooled[192];
    for (int i = t; i < 192; i += 256) z[i] = pooled[i] * inv;
    if (t == 0) z[192] = pt[0];
    __syncthreads();
    if (t < 96) {
        float a = f1b[t];
        for (int k = 0; k < 193; ++k) a = fmaf(z[k], f1w[k * 96 + t], a);
        z1[t] = lrelu(a, 0.01f);
    }
    __syncthreads();
    if (t < 96) {
        float a = f2b[t];
        for (int k = 0; k < 96; ++k) a = fmaf(z1[k], f2w[k * 96 + t], a);
        z2[t] = lrelu(a, 0.01f);
    }
    __syncthreads();
    if (t < 2) {
        float a = flb[t];
        for (int k = 0; k < 96; ++k) a = fmaf(z2[k], flw[k * 2 + t], a);
        out[t] = a;
    }
}

extern "C" void kernel_launch(void* const* d_in, const int* in_sizes, int n_in,
                              void* d_out, int out_size, void* d_ws, size_t ws_size,
                              hipStream_t stream) {
    (void)in_sizes; (void)n_in; (void)out_size; (void)ws_size;
    const float* x    = (const float*)d_in[0];
    const int*   ei   = (const int*)d_in[1];
    const float* ea   = (const float*)d_in[2];
    const float* pt   = (const float*)d_in[3];
    const float* llw  = (const float*)d_in[5];
    const float* llb  = (const float*)d_in[6];
    const float* lrw  = (const float*)d_in[7];
    const float* lrb  = (const float*)d_in[8];
    const float* lew  = (const float*)d_in[9];
    const float* attw = (const float*)d_in[10];
    const float* gbias= (const float*)d_in[11];
    const float* gw   = (const float*)d_in[12];
    const float* gb   = (const float*)d_in[13];
    const float* f1w  = (const float*)d_in[14];
    const float* f1b  = (const float*)d_in[15];
    const float* f2w  = (const float*)d_in[16];
    const float* f2b  = (const float*)d_in[17];
    const float* flw  = (const float*)d_in[18];
    const float* flb  = (const float*)d_in[19];
    float* out = (float*)d_out;

    char* w = (char*)d_ws;
    unsigned short* xlb = (unsigned short*)w; w += (size_t)NN * HF * 2;
    unsigned short* xrb = (unsigned short*)w; w += (size_t)NN * HF * 2;
    float* h1 = (float*)w;         w += (size_t)NN * FD * 4;
    int2* ell = (int2*)w;          w += (size_t)NN * ELLW * 8;
    int* deg = (int*)w;            w += (size_t)NN * 4;
    float* part = (float*)w;       w += (size_t)193 * GG_BLOCKS * 4;
    float* pooled = (float*)w;     w += 193 * 4;

    // ---- ELL build (2 dispatches; shared by both layers) ----
    zero_deg<<<SCAN_NB, 256, 0, stream>>>(deg);
    build_ell<<<(NE + 255) / 256, 256, 0, stream>>>(ei, ea, deg, ell);

    // ---- layer 0: transform + gather -> h1 ----
    node_transform<<<(NN + NTA - 1) / NTA, 256, 0, stream>>>(
        x, llw, llb, lrw, lrb, xlb, xrb);
    gat_gather<<<GG_BLOCKS, 256, 0, stream>>>(
        deg, ell, xlb, xrb, lew, attw, gbias, h1);

    // ---- layer 1: transform + gather fused with gate+pooling ----
    node_transform<<<(NN + NTA - 1) / NTA, 256, 0, stream>>>(
        h1, llw + (size_t)FD * HF, llb + HF,
        lrw + (size_t)FD * HF, lrb + HF, xlb, xrb);
    gat_gather_pool<<<GG_BLOCKS, 256, 0, stream>>>(
        deg, ell, xlb, xrb, lew + HF, attw + HF, gbias + FD,
        x, h1, gw, gb, part);

    // ---- pool reduce + MLP ----
    pool_reduce<<<193, 256, 0, stream>>>(part, pooled);
    mlp_kernel<<<1, 256, 0, stream>>>(pooled, pt, f1w, f1b, f2w, f2b, flw, flb, out);
}

// Round 19
// 197.358 us; speedup vs baseline: 1.1695x; 1.1695x over previous
//
#include <hip/hip_runtime.h>

#define NN 50000
#define NE 400000
#define FD 64
#define NH 2
#define HF 128   // H * F
#define ELLW 48  // ELL row width; P(Poisson(8) deg > 48) < 1e-15 per node
#define SCAN_NB ((NN + 255) / 256)
#define POOL_BLOCKS 512
#define NTA 64   // nodes per block in node_transform
#define GG_BLOCKS 2048   // persistent gather grid

__device__ __forceinline__ float lrelu(float x, float s) { return fmaxf(x, x * s); }

// ---- bf16 helpers: RNE pack, exact unpack ----
__device__ __forceinline__ unsigned short f2bf(float f) {
    unsigned u = __float_as_uint(f);
    return (unsigned short)((u + 0x7FFFu + ((u >> 16) & 1u)) >> 16);
}
__device__ __forceinline__ float2 bf2f(unsigned u) {
    return make_float2(__uint_as_float(u << 16), __uint_as_float(u & 0xFFFF0000u));
}
__device__ __forceinline__ float4 bfx4(unsigned lo, unsigned hi) {
    const float2 a = bf2f(lo), b = bf2f(hi);
    return make_float4(a.x, a.y, b.x, b.y);
}

// ================= ELL build: 2 dispatches total =================
__global__ void zero_deg(int* __restrict__ deg) {
    const int i = blockIdx.x * 256 + threadIdx.x;
    if (i < NN) deg[i] = 0;
}

__global__ void build_ell(const int* __restrict__ ei, const float* __restrict__ ea,
                          int* __restrict__ deg, int2* __restrict__ ell) {
    const int t = blockIdx.x * blockDim.x + threadIdx.x;
    if (t >= NE) return;
    const int d = ei[NE + t];
    const int r = atomicAdd(&deg[d], 1);
    ell[(size_t)d * ELLW + r] = make_int2(ei[t], __float_as_int(ea[t]));
}

// ---- per-layer GEMM: [xl|xr] = hin @ [Wl|Wr] + [bl|br] ----
__global__ __launch_bounds__(256) void node_transform(
    const float* __restrict__ hin,
    const float* __restrict__ Wl, const float* __restrict__ bl,
    const float* __restrict__ Wr, const float* __restrict__ br,
    unsigned short* __restrict__ xlb, unsigned short* __restrict__ xrb) {
    __shared__ float sA[FD][68];
    const int t = threadIdx.x;
    const int n0 = blockIdx.x * NTA;
    for (int idx = t; idx < NTA * 16; idx += 256) {
        const int n = idx & 63;
        const int kq = (idx >> 6) << 2;
        const int ni = n0 + n;
        const float4 v = (ni < NN) ? *(const float4*)(hin + (size_t)ni * FD + kq)
                                   : make_float4(0.f, 0.f, 0.f, 0.f);
        sA[kq][n] = v.x; sA[kq + 1][n] = v.y;
        sA[kq + 2][n] = v.z; sA[kq + 3][n] = v.w;
    }
    __syncthreads();
    const int q = t & 63;
    const int g = t >> 6;
    const int c0 = q << 2;
    const bool isR = c0 >= 128;
    const int cc = isR ? c0 - 128 : c0;
    const float* __restrict__ W = isR ? Wr : Wl;
    const float4 bv = isR ? *(const float4*)(br + cc) : *(const float4*)(bl + cc);
    unsigned short* __restrict__ dst = isR ? xrb : xlb;
    float acc[16][4];
#pragma unroll
    for (int i = 0; i < 16; ++i) {
        acc[i][0] = bv.x; acc[i][1] = bv.y; acc[i][2] = bv.z; acc[i][3] = bv.w;
    }
    const int nb = g << 4;
#pragma unroll 4
    for (int k = 0; k < FD; ++k) {
        const float4 w = *(const float4*)(W + k * HF + cc);
        const float4 a0 = *(const float4*)(&sA[k][nb]);
        const float4 a1 = *(const float4*)(&sA[k][nb + 4]);
        const float4 a2 = *(const float4*)(&sA[k][nb + 8]);
        const float4 a3 = *(const float4*)(&sA[k][nb + 12]);
        const float av[16] = {a0.x, a0.y, a0.z, a0.w, a1.x, a1.y, a1.z, a1.w,
                              a2.x, a2.y, a2.z, a2.w, a3.x, a3.y, a3.z, a3.w};
#pragma unroll
        for (int i = 0; i < 16; ++i) {
            acc[i][0] = fmaf(av[i], w.x, acc[i][0]);
            acc[i][1] = fmaf(av[i], w.y, acc[i][1]);
            acc[i][2] = fmaf(av[i], w.z, acc[i][2]);
            acc[i][3] = fmaf(av[i], w.w, acc[i][3]);
        }
    }
    const int xoff = (cc < 64) ? (cc << 1) : (((cc - 64) << 1) + 4);
#pragma unroll
    for (int i = 0; i < 16; ++i) {
        const int n = n0 + nb + i;
        if (n >= NN) continue;
        uint2 pk;
        pk.x = (unsigned)f2bf(acc[i][0]) | ((unsigned)f2bf(acc[i][1]) << 16);
        pk.y = (unsigned)f2bf(acc[i][2]) | ((unsigned)f2bf(acc[i][3]) << 16);
        *(uint2*)(dst + (size_t)n * HF + xoff) = pk;
    }
}

// ---- one edge-slot update; VALID folds at compile time on the hot path ----
__device__ __forceinline__ void gat_edge(
    bool valid, int lane, float eav, uint4 L,
    const float4& we0, const float4& we1, const float4& aw0, const float4& aw1,
    const float4& xr0, const float4& xr1,
    float4& a0, float4& a1, float& d0, float& d1) {
    const float4 xls0 = bfx4(L.x, L.y);
    const float4 xls1 = bfx4(L.z, L.w);
    float p0, p1, t;
    t = lrelu(fmaf(eav, we0.x, xls0.x + xr0.x), 0.2f); p0 = t * aw0.x;
    t = lrelu(fmaf(eav, we0.y, xls0.y + xr0.y), 0.2f); p0 = fmaf(t, aw0.y, p0);
    t = lrelu(fmaf(eav, we0.z, xls0.z + xr0.z), 0.2f); p0 = fmaf(t, aw0.z, p0);
    t = lrelu(fmaf(eav, we0.w, xls0.w + xr0.w), 0.2f); p0 = fmaf(t, aw0.w, p0);
    t = lrelu(fmaf(eav, we1.x, xls1.x + xr1.x), 0.2f); p1 = t * aw1.x;
    t = lrelu(fmaf(eav, we1.y, xls1.y + xr1.y), 0.2f); p1 = fmaf(t, aw1.y, p1);
    t = lrelu(fmaf(eav, we1.z, xls1.z + xr1.z), 0.2f); p1 = fmaf(t, aw1.z, p1);
    t = lrelu(fmaf(eav, we1.w, xls1.w + xr1.w), 0.2f); p1 = fmaf(t, aw1.w, p1);
    // packed dual-head 16-lane reduce: 5 shfl
    const bool hi = (lane & 8) != 0;
    float send = hi ? p0 : p1;
    float got = __shfl_xor(send, 8);
    float q = hi ? (p1 + got) : (p0 + got);
    q += __shfl_xor(q, 4);
    q += __shfl_xor(q, 2);
    q += __shfl_xor(q, 1);
    const float oth = __shfl_xor(q, 8);
    const float s0 = hi ? oth : q;
    const float s1 = hi ? q : oth;
    const float w0 = valid ? __expf(s0) : 0.f;
    const float w1 = valid ? __expf(s1) : 0.f;
    a0.x = fmaf(w0, xls0.x, a0.x);
    a0.y = fmaf(w0, xls0.y, a0.y);
    a0.z = fmaf(w0, xls0.z, a0.z);
    a0.w = fmaf(w0, xls0.w, a0.w);
    d0 += w0;
    a1.x = fmaf(w1, xls1.x, a1.x);
    a1.y = fmaf(w1, xls1.y, a1.y);
    a1.z = fmaf(w1, xls1.z, a1.z);
    a1.w = fmaf(w1, xls1.w, a1.w);
    d1 += w1;
}

// ---- persistent gather with cross-node first-group ELL prefetch ----
__global__ __launch_bounds__(256) void gat_gather(
    const int* __restrict__ deg, const int2* __restrict__ ell,
    const unsigned short* __restrict__ xlb, const unsigned short* __restrict__ xrb,
    const float* __restrict__ We, const float* __restrict__ att,
    const float* __restrict__ bias, float* __restrict__ hout) {
    const int t = threadIdx.x;
    const int lane = t & 63;
    const int slot = lane >> 4;
    const int fo = (lane & 15) << 2;
    const float4 we0 = *(const float4*)(We + fo);
    const float4 we1 = *(const float4*)(We + 64 + fo);
    const float4 aw0 = *(const float4*)(att + fo);
    const float4 aw1 = *(const float4*)(att + 64 + fo);
    const float4 bv = *(const float4*)(bias + fo);
    const int stride = (GG_BLOCKS * 256) >> 6;
    int wid = (blockIdx.x * 256 + t) >> 6;
    int dg = 0;
    int2 pA = make_int2(0, 0), pB = make_int2(0, 0);
    if (wid < NN) {
        dg = deg[wid];
        pA = ell[(size_t)wid * ELLW + slot];       // may hold padding garbage
        pB = ell[(size_t)wid * ELLW + 4 + slot];   // sanitized at use
    }

    while (wid < NN) {
        const int nxt = wid + stride;
        int dgn = 0;
        int2 nA = make_int2(0, 0), nB = make_int2(0, 0);
        if (nxt < NN) {
            dgn = deg[nxt];
            nA = ell[(size_t)nxt * ELLW + slot];   // prefetch next node's group 0
            nB = ell[(size_t)nxt * ELLW + 4 + slot];
        }
        const uint4 xrp = *(const uint4*)(xrb + (size_t)wid * HF + (fo << 1));
        const float4 xr0 = bfx4(xrp.x, xrp.y);
        const float4 xr1 = bfx4(xrp.z, xrp.w);
        const int e0 = wid * ELLW;
        const int e1 = e0 + dg;
        float d0 = 0.f, d1 = 0.f;
        float4 a0 = {0.f, 0.f, 0.f, 0.f}, a1 = {0.f, 0.f, 0.f, 0.f};
        // group 0 from prefetched registers (masked; sanitize padding garbage)
        {
            const bool vA = slot < dg, vB = 4 + slot < dg;
            const int sA = vA ? pA.x : 0;
            const int sB = vB ? pB.x : 0;
            const uint4 LA = *(const uint4*)(xlb + (size_t)sA * HF + (fo << 1));
            const uint4 LB = *(const uint4*)(xlb + (size_t)sB * HF + (fo << 1));
            gat_edge(vA, lane, __int_as_float(pA.y), LA, we0, we1, aw0, aw1,
                     xr0, xr1, a0, a1, d0, d1);
            gat_edge(vB, lane, __int_as_float(pB.y), LB, we0, we1, aw0, aw1,
                     xr0, xr1, a0, a1, d0, d1);
        }
        int eb = e0 + 8;
        for (; eb + 8 <= e1; eb += 8) {      // full groups: no masking
            const int2 seA = ell[eb + slot];
            const int2 seB = ell[eb + 4 + slot];
            const uint4 LA = *(const uint4*)(xlb + (size_t)seA.x * HF + (fo << 1));
            const uint4 LB = *(const uint4*)(xlb + (size_t)seB.x * HF + (fo << 1));
            gat_edge(true, lane, __int_as_float(seA.y), LA, we0, we1, aw0, aw1,
                     xr0, xr1, a0, a1, d0, d1);
            gat_edge(true, lane, __int_as_float(seB.y), LB, we0, we1, aw0, aw1,
                     xr0, xr1, a0, a1, d0, d1);
        }
        if (eb < e1) {   // masked tail; only reached when dg > 8 so ell[e0] is real
            const int myA = eb + slot, myB = eb + 4 + slot;
            const bool vA = myA < e1, vB = myB < e1;
            const int2 seA = ell[vA ? myA : e0];
            const int2 seB = ell[vB ? myB : e0];
            const uint4 LA = *(const uint4*)(xlb + (size_t)seA.x * HF + (fo << 1));
            const uint4 LB = *(const uint4*)(xlb + (size_t)seB.x * HF + (fo << 1));
            gat_edge(vA, lane, __int_as_float(seA.y), LA, we0, we1, aw0, aw1,
                     xr0, xr1, a0, a1, d0, d1);
            gat_edge(vB, lane, __int_as_float(seB.y), LB, we0, we1, aw0, aw1,
                     xr0, xr1, a0, a1, d0, d1);
        }
#pragma unroll
        for (int o = 16; o <= 32; o <<= 1) {
            d0 += __shfl_xor(d0, o);
            d1 += __shfl_xor(d1, o);
            a0.x += __shfl_xor(a0.x, o); a0.y += __shfl_xor(a0.y, o);
            a0.z += __shfl_xor(a0.z, o); a0.w += __shfl_xor(a0.w, o);
            a1.x += __shfl_xor(a1.x, o); a1.y += __shfl_xor(a1.y, o);
            a1.z += __shfl_xor(a1.z, o); a1.w += __shfl_xor(a1.w, o);
        }
        if (slot == 0) {
            const float i0 = d0 > 0.f ? 1.f / d0 : 0.f;
            const float i1 = d1 > 0.f ? 1.f / d1 : 0.f;
            float4 rr;
            rr.x = lrelu(fmaf(0.5f, fmaf(a0.x, i0, a1.x * i1), bv.x), 0.01f);
            rr.y = lrelu(fmaf(0.5f, fmaf(a0.y, i0, a1.y * i1), bv.y), 0.01f);
            rr.z = lrelu(fmaf(0.5f, fmaf(a0.z, i0, a1.z * i1), bv.z), 0.01f);
            rr.w = lrelu(fmaf(0.5f, fmaf(a0.w, i0, a1.w * i1), bv.w), 0.01f);
            *(float4*)(hout + (size_t)wid * FD + fo) = rr;
        }
        wid = nxt;
        dg = dgn;
        pA = nA;
        pB = nB;
    }
}

// ---- fused gate + weighted pooling -> TRANSPOSED per-block partials ----
__global__ void pool_kernel(const float* __restrict__ x, const float* __restrict__ h1,
                            const float* __restrict__ h2, const float* __restrict__ gw,
                            const float* __restrict__ gb, float* __restrict__ part) {
    __shared__ float sp[193];
    const int t = threadIdx.x;
    if (t < 193) sp[t] = 0.f;
    __syncthreads();
    const int lane = t & 63;
    const int wid = (blockIdx.x * blockDim.x + t) >> 6;
    const int nw = (POOL_BLOCKS * 256) >> 6;
    const float w0 = gw[lane], w1 = gw[64 + lane], w2 = gw[128 + lane];
    const float gbv = gb[0];
    float p0 = 0.f, p1 = 0.f, p2 = 0.f, es = 0.f;
    for (int n = wid; n < NN; n += nw) {
        const size_t b = (size_t)n * FD + lane;
        const float xv = x[b], h1v = h1[b], h2v = h2[b];
        float v = xv * w0 + h1v * w1 + h2v * w2;
#pragma unroll
        for (int o = 32; o; o >>= 1) v += __shfl_xor(v, o);
        const float e = __expf(lrelu(v + gbv, 0.01f));   // uniform across lanes
        p0 = fmaf(e, xv, p0);
        p1 = fmaf(e, h1v, p1);
        p2 = fmaf(e, h2v, p2);
        es += e;
    }
    atomicAdd(&sp[lane], p0);
    atomicAdd(&sp[64 + lane], p1);
    atomicAdd(&sp[128 + lane], p2);
    if (lane == 0) atomicAdd(&sp[192], es);
    __syncthreads();
    if (t < 193) part[(size_t)t * POOL_BLOCKS + blockIdx.x] = sp[t];
}

// ---- reduce transposed partials: block e sums part[e*POOL_BLOCKS ..] ----
__global__ void pool_reduce(const float* __restrict__ part, float* __restrict__ pooled) {
    __shared__ float ws[4];
    const int e = blockIdx.x;   // 0..192
    const int t = threadIdx.x;  // 256
    float s = 0.f;
#pragma unroll
    for (int b = t; b < POOL_BLOCKS; b += 256) s += part[(size_t)e * POOL_BLOCKS + b];
#pragma unroll
    for (int o = 32; o; o >>= 1) s += __shfl_xor(s, o);
    if ((t & 63) == 0) ws[t >> 6] = s;
    __syncthreads();
    if (t == 0) pooled[e] = ws[0] + ws[1] + ws[2] + ws[3];
}

// ---- final tiny MLP: z(193) -> 96 -> 96 -> 2 ----
__global__ void mlp_kernel(const float* __restrict__ pooled, const float* __restrict__ pt,
                           const float* __restrict__ f1w, const float* __restrict__ f1b,
                           const float* __restrict__ f2w, const float* __restrict__ f2b,
                           const float* __restrict__ flw, const float* __restrict__ flb,
                           float* __restrict__ out) {
    __shared__ float z[193], z1[96], z2[96];
    const int t = threadIdx.x;  // 256
    const float inv = 1.f / pooled[192];
    for (int i = t; i < 192; i += 256) z[i] = pooled[i] * inv;
    if (t == 0) z[192] = pt[0];
    __syncthreads();
    if (t < 96) {
        float a = f1b[t];
        for (int k = 0; k < 193; ++k) a = fmaf(z[k], f1w[k * 96 + t], a);
        z1[t] = lrelu(a, 0.01f);
    }
    __syncthreads();
    if (t < 96) {
        float a = f2b[t];
        for (int k = 0; k < 96; ++k) a = fmaf(z1[k], f2w[k * 96 + t], a);
        z2[t] = lrelu(a, 0.01f);
    }
    __syncthreads();
    if (t < 2) {
        float a = flb[t];
        for (int k = 0; k < 96; ++k) a = fmaf(z2[k], flw[k * 2 + t], a);
        out[t] = a;
    }
}

extern "C" void kernel_launch(void* const* d_in, const int* in_sizes, int n_in,
                              void* d_out, int out_size, void* d_ws, size_t ws_size,
                              hipStream_t stream) {
    (void)in_sizes; (void)n_in; (void)out_size; (void)ws_size;
    const float* x    = (const float*)d_in[0];
    const int*   ei   = (const int*)d_in[1];
    const float* ea   = (const float*)d_in[2];
    const float* pt   = (const float*)d_in[3];
    const float* llw  = (const float*)d_in[5];
    const float* llb  = (const float*)d_in[6];
    const float* lrw  = (const float*)d_in[7];
    const float* lrb  = (const float*)d_in[8];
    const float* lew  = (const float*)d_in[9];
    const float* attw = (const float*)d_in[10];
    const float* gbias= (const float*)d_in[11];
    const float* gw   = (const float*)d_in[12];
    const float* gb   = (const float*)d_in[13];
    const float* f1w  = (const float*)d_in[14];
    const float* f1b  = (const float*)d_in[15];
    const float* f2w  = (const float*)d_in[16];
    const float* f2b  = (const float*)d_in[17];
    const float* flw  = (const float*)d_in[18];
    const float* flb  = (const float*)d_in[19];
    float* out = (float*)d_out;

    char* w = (char*)d_ws;
    unsigned short* xlb = (unsigned short*)w; w += (size_t)NN * HF * 2;
    unsigned short* xrb = (unsigned short*)w; w += (size_t)NN * HF * 2;
    float* h1 = (float*)w;         w += (size_t)NN * FD * 4;
    float* h2 = (float*)w;         w += (size_t)NN * FD * 4;
    int2* ell = (int2*)w;          w += (size_t)NN * ELLW * 8;
    int* deg = (int*)w;            w += (size_t)NN * 4;
    float* part = (float*)w;       w += (size_t)193 * POOL_BLOCKS * 4;
    float* pooled = (float*)w;     w += 193 * 4;

    // ---- ELL build (2 dispatches; shared by both layers) ----
    zero_deg<<<SCAN_NB, 256, 0, stream>>>(deg);
    build_ell<<<(NE + 255) / 256, 256, 0, stream>>>(ei, ea, deg, ell);

    // ---- 2 GAT layers ----
    for (int p = 0; p < 2; ++p) {
        const float* hin = (p == 0) ? x : h1;
        float* hout = (p == 0) ? h1 : h2;
        node_transform<<<(NN + NTA - 1) / NTA, 256, 0, stream>>>(
            hin, llw + (size_t)p * FD * HF, llb + (size_t)p * HF,
            lrw + (size_t)p * FD * HF, lrb + (size_t)p * HF, xlb, xrb);
        gat_gather<<<GG_BLOCKS, 256, 0, stream>>>(
            deg, ell, xlb, xrb,
            lew + (size_t)p * HF, attw + (size_t)p * HF,
            gbias + (size_t)p * FD, hout);
    }

    // ---- pooling partials + reduce + MLP ----
    pool_kernel<<<POOL_BLOCKS, 256, 0, stream>>>(x, h1, h2, gw, gb, part);
    pool_reduce<<<193, 256, 0, stream>>>(part, pooled);
    mlp_kernel<<<1, 256, 0, stream>>>(pooled, pt, f1w, f1b, f2w, f2b, flw, flb, out);
}